// Round 8
// baseline (67.409 us; speedup 1.0000x reference)
//
#include <hip/hip_runtime.h>

// Problem dims (fixed by reference setup_inputs):
#define BATCH 1024
#define NSEQ  512
#define NF    64
#define TBL_N (NSEQ + 1)   // counts range 0..512
#define HIST_BINS 1024     // ids in [0,1000)

#define HOT 32             // table rows staged in LDS (counts ~Poisson(0.5), max~7)
#define TBL_BLOCKS ((TBL_N + 3) / 4)   // 129 blocks x (4 c-values * 64 threads)

typedef float f32x4 __attribute__((ext_vector_type(4)));  // for nontemporal builtin

// ---------------------------------------------------------------------------
// Kernel 1: full lookup table into workspace.
// tbl[c][g] = b2[g] + sum_f relu(c*W1[f]+b1[f]) * W2[f][g]
// ---------------------------------------------------------------------------
__global__ __launch_bounds__(256) void build_table_kernel(
        const float* __restrict__ W1,
        const float* __restrict__ b1,
        const float* __restrict__ W2,
        const float* __restrict__ b2,
        float* __restrict__ tbl) {
    const int c = blockIdx.x * 4 + (threadIdx.x >> 6);
    const int g = threadIdx.x & 63;
    if (c >= TBL_N) return;
    const float cf = (float)c;
    float acc = b2[g];
#pragma unroll 8
    for (int f = 0; f < NF; ++f) {
        float h = fmaxf(cf * W1[f] + b1[f], 0.0f);
        acc += h * W2[f * NF + g];
    }
    tbl[c * NF + g] = acc;
}

// ---------------------------------------------------------------------------
// Kernel 2: writer (identical to R7 except stores are NONTEMPORAL).
// Block 2*row+which owns batch-row `row` of tensor `which`.
// Hot loop: ds_read_b32 + 2x ds_read_b128 + 4 adds + nt global_store_dwordx4.
// ---------------------------------------------------------------------------
__global__ __launch_bounds__(256) void expand_kernel(
        const int* __restrict__ src_ids,
        const int* __restrict__ dst_ids,
        const float* __restrict__ g_tbl,
        float* __restrict__ out) {
    __shared__ int            hist_s[HIST_BINS];
    __shared__ int            hist_d[HIST_BINS];
    __shared__ float          s_tbl[HOT * NF];      // 8 KB, stride 64
    __shared__ ushort2        s_off[NSEQ];          // clamped byte offsets (c1,c2)
    __shared__ unsigned short s_ovf[NSEQ];          // overflow positions
    __shared__ int            s_novf;

    const int t     = threadIdx.x;
    const int which = blockIdx.x & 1;    // 0 = src-encoding, 1 = dst-encoding
    const int row   = blockIdx.x >> 1;

    const int* __restrict__ own_ids = (which == 0) ? src_ids : dst_ids;

    // zero histograms + ovf counter
#pragma unroll
    for (int i = t; i < HIST_BINS; i += 256) { hist_s[i] = 0; hist_d[i] = 0; }
    if (t == 0) s_novf = 0;

    // copy hot table rows global -> LDS (2 float4 per thread)
    {
        const float4* __restrict__ g4 = (const float4*)g_tbl;
        float4* __restrict__ l4 = (float4*)s_tbl;
#pragma unroll
        for (int i = t; i < HOT * NF / 4; i += 256) l4[i] = g4[i];
    }
    __syncthreads();

    // histogram both rows (guard padded id = -1)
#pragma unroll
    for (int i = t; i < NSEQ; i += 256) {
        int si = src_ids[(size_t)row * NSEQ + i];
        int di = dst_ids[(size_t)row * NSEQ + i];
        if (si >= 0) atomicAdd(&hist_s[si], 1);
        if (di >= 0) atomicAdd(&hist_d[di], 1);
    }
    __syncthreads();

    // per-position clamped byte offsets for THIS tensor; overflow -> list
#pragma unroll
    for (int i = t; i < NSEQ; i += 256) {
        int id = own_ids[(size_t)row * NSEQ + i];
        int own = 0, cross = 0;
        if (id >= 0) {
            own   = (which == 0) ? hist_s[id] : hist_d[id];
            cross = (which == 0) ? hist_d[id] : hist_s[id];
        }
        if (own >= HOT || cross >= HOT) {
            int k = atomicAdd(&s_novf, 1);
            s_ovf[k] = (unsigned short)i;
        }
        ushort2 off;
        off.x = (unsigned short)(min(own,   HOT - 1) * (NF * 4));
        off.y = (unsigned short)(min(cross, HOT - 1) * (NF * 4));
        s_off[i] = off;
    }
    __syncthreads();

    // ---- hot store stream: nontemporal stores, LDS-only gathers ----
    f32x4* __restrict__ o =
        (f32x4*)(out + ((size_t)which * BATCH + row) * NSEQ * NF);
    const char* __restrict__ tb = (const char*)s_tbl;
    const int NV = NSEQ * NF / 4;   // 8192 float4
#pragma unroll 4
    for (int e = t; e < NV; e += 256) {
        const int n  = e >> 4;           // position (16 float4 per position)
        const int fb = (e & 15) << 4;    // byte offset within row
        const ushort2 c = s_off[n];
        const f32x4 a0 = *(const f32x4*)(tb + (int)c.x + fb);
        const f32x4 a1 = *(const f32x4*)(tb + (int)c.y + fb);
        __builtin_nontemporal_store(a0 + a1, &o[e]);
    }

    // ---- rare fixup for counts >= HOT (reads global table) ----
    __syncthreads();
    const int novf = s_novf;
    if (novf > 0) {
        const f32x4* __restrict__ g4 = (const f32x4*)g_tbl;
        for (int k = t >> 4; k < novf; k += 16) {
            const int i  = s_ovf[k];
            const int f4 = t & 15;
            const int id = own_ids[(size_t)row * NSEQ + i];
            int own = 0, cross = 0;
            if (id >= 0) {
                own   = (which == 0) ? hist_s[id] : hist_d[id];
                cross = (which == 0) ? hist_d[id] : hist_s[id];
            }
            f32x4 a0 = g4[own * (NF / 4) + f4];
            f32x4 a1 = g4[cross * (NF / 4) + f4];
            __builtin_nontemporal_store(a0 + a1, &o[i * 16 + f4]);
        }
    }
}

extern "C" void kernel_launch(void* const* d_in, const int* in_sizes, int n_in,
                              void* d_out, int out_size, void* d_ws, size_t ws_size,
                              hipStream_t stream) {
    const int*   src_ids = (const int*)d_in[0];
    const int*   dst_ids = (const int*)d_in[1];
    const float* W1 = (const float*)d_in[2];   // [1, F]
    const float* b1 = (const float*)d_in[3];   // [F]
    const float* W2 = (const float*)d_in[4];   // [F, F]
    const float* b2 = (const float*)d_in[5];   // [F]

    float* out = (float*)d_out;   // [2, B, N, F] flat (src encoding, then dst)
    float* tbl = (float*)d_ws;    // TBL_N * NF f32 = 131,328 B

    build_table_kernel<<<TBL_BLOCKS, 256, 0, stream>>>(W1, b1, W2, b2, tbl);
    expand_kernel<<<2 * BATCH, 256, 0, stream>>>(src_ids, dst_ids, tbl, out);
}

// Round 9
// 51.615 us; speedup vs baseline: 1.3060x; 1.3060x over previous
//
#include <hip/hip_runtime.h>

// Problem dims (fixed by reference setup_inputs):
#define BATCH 1024
#define NSEQ  512
#define NF    64
#define TBL_N (NSEQ + 1)   // counts range 0..512
#define HIST_BINS 1024     // ids in [0,1000)

#define HOT 32             // table rows staged in LDS (counts ~Poisson(0.5), max~7)
#define HALF 256           // positions per writer block (half a row)
#define TBL_BLOCKS ((TBL_N + 3) / 4)

// ---------------------------------------------------------------------------
// Kernel 1: full lookup table into workspace.
// tbl[c][g] = b2[g] + sum_f relu(c*W1[f]+b1[f]) * W2[f][g]
// ---------------------------------------------------------------------------
__global__ __launch_bounds__(256) void build_table_kernel(
        const float* __restrict__ W1,
        const float* __restrict__ b1,
        const float* __restrict__ W2,
        const float* __restrict__ b2,
        float* __restrict__ tbl) {
    const int c = blockIdx.x * 4 + (threadIdx.x >> 6);
    const int g = threadIdx.x & 63;
    if (c >= TBL_N) return;
    const float cf = (float)c;
    float acc = b2[g];
#pragma unroll 8
    for (int f = 0; f < NF; ++f) {
        float h = fmaxf(cf * W1[f] + b1[f], 0.0f);
        acc += h * W2[f * NF + g];
    }
    tbl[c * NF + g] = acc;
}

// ---------------------------------------------------------------------------
// Kernel 2: pipelined writer. 4096 blocks = TWO generations of 8 blocks/CU;
// generation-2 prologues overlap generation-1 store streams.
// Block index: b = which*2048 + row*2 + half  (consecutive blocks write
// consecutive 64 KB spans -> fill-kernel store locality).
// Per block: id loads issued at instruction 0 (latency hides under LDS
// zeroing + table copy), both row histograms, clamped LDS byte offsets for
// its HALF positions, then a fully-unrolled 16-iteration store loop whose
// vmem pipe carries ONLY stores (plain float4 -- nt confirmed -32% in R8).
// LDS ~17.5 KB -> 8 blocks/CU (wave-limited).
// ---------------------------------------------------------------------------
__global__ __launch_bounds__(256) void expand_kernel(
        const int* __restrict__ src_ids,
        const int* __restrict__ dst_ids,
        const float* __restrict__ g_tbl,
        float* __restrict__ out) {
    __shared__ int            hist_s[HIST_BINS];
    __shared__ int            hist_d[HIST_BINS];
    __shared__ float          s_tbl[HOT * NF];   // 8 KB
    __shared__ ushort2        s_off[HALF];       // clamped byte offsets (own,cross)
    __shared__ unsigned short s_ovf[HALF];
    __shared__ int            s_novf;

    const int t     = threadIdx.x;
    const int half  = blockIdx.x & 1;
    const int row   = (blockIdx.x >> 1) & (BATCH - 1);
    const int which = blockIdx.x >> 11;          // 0 = src-encoding, 1 = dst

    // ---- issue id loads FIRST: latency hides under LDS prologue ----
    const size_t rb = (size_t)row * NSEQ;
    const int si0 = src_ids[rb + t];             // position t       (half 0)
    const int si1 = src_ids[rb + t + 256];       // position t+256   (half 1)
    const int di0 = dst_ids[rb + t];
    const int di1 = dst_ids[rb + t + 256];

    // zero histograms + ovf counter
#pragma unroll
    for (int i = t; i < HIST_BINS; i += 256) { hist_s[i] = 0; hist_d[i] = 0; }
    if (t == 0) s_novf = 0;

    // copy hot table rows global -> LDS (2 float4 per thread, L2-hot)
    {
        const float4* __restrict__ g4 = (const float4*)g_tbl;
        float4* __restrict__ l4 = (float4*)s_tbl;
#pragma unroll
        for (int i = t; i < HOT * NF / 4; i += 256) l4[i] = g4[i];
    }
    __syncthreads();

    // histogram both rows (guard padded id = -1)
    if (si0 >= 0) atomicAdd(&hist_s[si0], 1);
    if (si1 >= 0) atomicAdd(&hist_s[si1], 1);
    if (di0 >= 0) atomicAdd(&hist_d[di0], 1);
    if (di1 >= 0) atomicAdd(&hist_d[di1], 1);
    __syncthreads();

    // per-position clamped byte offsets for THIS tensor's HALF; ovf -> list
    {
        const int id = (which == 0) ? (half ? si1 : si0) : (half ? di1 : di0);
        int own = 0, cross = 0;
        if (id >= 0) {
            own   = (which == 0) ? hist_s[id] : hist_d[id];
            cross = (which == 0) ? hist_d[id] : hist_s[id];
        }
        if (own >= HOT || cross >= HOT) {
            int k = atomicAdd(&s_novf, 1);
            s_ovf[k] = (unsigned short)t;
        }
        ushort2 off;
        off.x = (unsigned short)(min(own,   HOT - 1) * (NF * 4));
        off.y = (unsigned short)(min(cross, HOT - 1) * (NF * 4));
        s_off[t] = off;
    }
    __syncthreads();

    // ---- hot store stream: 16 iterations, vmem pipe = stores only ----
    float4* __restrict__ o = (float4*)(out +
        (((size_t)which * BATCH + row) * NSEQ + (size_t)half * HALF) * NF);
    const char* __restrict__ tb = (const char*)s_tbl;

    // preload this thread's 16 offset pairs (n = (t>>4) + k*16)
    ushort2 offs[16];
#pragma unroll
    for (int k = 0; k < 16; ++k) offs[k] = s_off[(t >> 4) + k * 16];

    const int fb = (t & 15) << 4;   // byte offset within a table row
#pragma unroll
    for (int k = 0; k < 16; ++k) {
        const int e = t + k * 256;
        const float4 a0 = *(const float4*)(tb + (int)offs[k].x + fb);
        const float4 a1 = *(const float4*)(tb + (int)offs[k].y + fb);
        o[e] = make_float4(a0.x + a1.x, a0.y + a1.y, a0.z + a1.z, a0.w + a1.w);
    }

    // ---- rare fixup for counts >= HOT (reads global table) ----
    __syncthreads();
    const int novf = s_novf;
    if (novf > 0) {
        const float4* __restrict__ g4 = (const float4*)g_tbl;
        for (int k = t >> 4; k < novf; k += 16) {
            const int i  = s_ovf[k];                 // local position in half
            const int f4 = t & 15;
            const int id = (which == 0) ? src_ids[rb + half * HALF + i]
                                        : dst_ids[rb + half * HALF + i];
            int own = 0, cross = 0;
            if (id >= 0) {
                own   = (which == 0) ? hist_s[id] : hist_d[id];
                cross = (which == 0) ? hist_d[id] : hist_s[id];
            }
            float4 a0 = g4[own * (NF / 4) + f4];
            float4 a1 = g4[cross * (NF / 4) + f4];
            o[i * 16 + f4] = make_float4(a0.x + a1.x, a0.y + a1.y,
                                         a0.z + a1.z, a0.w + a1.w);
        }
    }
}

extern "C" void kernel_launch(void* const* d_in, const int* in_sizes, int n_in,
                              void* d_out, int out_size, void* d_ws, size_t ws_size,
                              hipStream_t stream) {
    const int*   src_ids = (const int*)d_in[0];
    const int*   dst_ids = (const int*)d_in[1];
    const float* W1 = (const float*)d_in[2];   // [1, F]
    const float* b1 = (const float*)d_in[3];   // [F]
    const float* W2 = (const float*)d_in[4];   // [F, F]
    const float* b2 = (const float*)d_in[5];   // [F]

    float* out = (float*)d_out;   // [2, B, N, F] flat (src encoding, then dst)
    float* tbl = (float*)d_ws;    // TBL_N * NF f32 = 131,328 B

    build_table_kernel<<<TBL_BLOCKS, 256, 0, stream>>>(W1, b1, W2, b2, tbl);
    expand_kernel<<<2 * 2 * BATCH, 256, 0, stream>>>(src_ids, dst_ids, tbl, out);
}